// Round 4
// baseline (219.625 us; speedup 1.0000x reference)
//
#include <hip/hip_runtime.h>

#define N_NODES 32768
#define N_EDGES 16384
#define DEG 4
#define KPE 8
#define DIM 128
#define EDIM 64

typedef float f32x4 __attribute__((ext_vector_type(4)));
typedef __bf16 bf16x8 __attribute__((ext_vector_type(8)));
typedef __bf16 bf16x2 __attribute__((ext_vector_type(2)));
typedef unsigned short u16x8 __attribute__((ext_vector_type(8)));
typedef unsigned int u32;
typedef unsigned int u32x4 __attribute__((ext_vector_type(4)));
typedef int i32x4 __attribute__((ext_vector_type(4)));

static __device__ __forceinline__ unsigned short f2bf(float f) {
  union { float f; unsigned int u; } v; v.f = f;
  unsigned int r = (v.u + 0x7FFFu + ((v.u >> 16) & 1u)) >> 16;
  return (unsigned short)r;
}
static __device__ __forceinline__ float bflo(unsigned int v) {
  union { unsigned int u; float f; } x; x.u = v << 16; return x.f;
}
static __device__ __forceinline__ float bfhi(unsigned int v) {
  union { unsigned int u; float f; } x; x.u = v & 0xffff0000u; return x.f;
}

#if __has_builtin(__builtin_amdgcn_fdot2_f32_bf16)
static __device__ __forceinline__ float dot2bf(unsigned int a, unsigned int b, float c) {
  return __builtin_amdgcn_fdot2_f32_bf16(
      __builtin_bit_cast(bf16x2, a), __builtin_bit_cast(bf16x2, b), c, false);
}
#else
static __device__ __forceinline__ float dot2bf(unsigned int a, unsigned int b, float c) {
  c = fmaf(bflo(a), bflo(b), c);
  return fmaf(bfhi(a), bfhi(b), c);
}
#endif

// ---------------- weight combine + uidx flatten (unchanged) -------------------
__global__ __launch_bounds__(256) void wprep_kernel(
    const float* __restrict__ Wq, const float* __restrict__ Wk,
    const float* __restrict__ Wv, const float* __restrict__ Wlin,
    const float* __restrict__ Wedge, const float* __restrict__ Wo,
    const int* __restrict__ node_edges, const int* __restrict__ enodes,
    unsigned short* __restrict__ CW, unsigned short* __restrict__ CWE,
    unsigned short* __restrict__ Wob, int* __restrict__ uidx)
{
  int id = blockIdx.x * 256 + threadIdx.x;
  if (id < 384 * 128) {
    int j = id >> 7, i = id & 127;
    const float* wrow; float scale = 1.0f;
    if (j < 128)      { wrow = Wq + j * 128; scale = 0.25f; }
    else if (j < 256) { wrow = Wk + (j - 128) * 128; }
    else              { wrow = Wv + (j - 256) * 128; }
    float s = 0.f;
    #pragma unroll 8
    for (int m = 0; m < 128; ++m) s += wrow[m] * Wlin[m * 128 + i];
    CW[id] = f2bf(s * scale);
  } else if (id < 384 * 128 + 128 * 64) {
    int id2 = id - 384 * 128; int j = id2 >> 6, t = id2 & 63;
    float s = 0.f;
    #pragma unroll 8
    for (int m = 0; m < 128; ++m) s += Wk[j * 128 + m] * Wedge[m * 64 + t];
    CWE[id2] = f2bf(s);
  } else if (id < 384 * 128 + 128 * 64 + 128 * 128) {
    int id3 = id - (384 * 128 + 128 * 64);
    Wob[id3] = f2bf(Wo[id3]);
  } else {
    // uidx flatten: t = n*DEG + d in [0, 131072); blocks 288..799 land here.
    int t = id - (384 * 128 + 128 * 64 + 128 * 128);
    int e = node_edges[t];
    i32x4 a = *(const i32x4*)(enodes + (size_t)e * KPE);
    i32x4 b = *(const i32x4*)(enodes + (size_t)e * KPE + 4);
    *(i32x4*)(uidx + (size_t)t * KPE)     = a;
    *(i32x4*)(uidx + (size_t)t * KPE + 4) = b;
  }
}

// ---------------- G12: fused g1 + g2 (unchanged) ------------------------------
__global__ __launch_bounds__(256) void g12_kernel(
    const float* __restrict__ x, const unsigned short* __restrict__ CW,
    const float* __restrict__ bq, const float* __restrict__ bv,
    unsigned short* __restrict__ qb, unsigned short* __restrict__ Kb,
    unsigned short* __restrict__ Vb,
    const float* __restrict__ ea, const unsigned short* __restrict__ CWE,
    const float* __restrict__ bk, unsigned short* __restrict__ WeKb)
{
  const int wave = threadIdx.x >> 6, lane = threadIdx.x & 63;
  const int r16 = lane & 15, quad = lane >> 4;

  if (blockIdx.x < 512) {
    const int m0 = blockIdx.x * 64 + wave * 16;
    u16x8 av[4];
    const float* arow = x + (size_t)(m0 + r16) * DIM + quad * 8;
    #pragma unroll
    for (int kk = 0; kk < 4; ++kk) {
      float4 a0 = *(const float4*)(arow + kk * 32);
      float4 a1 = *(const float4*)(arow + kk * 32 + 4);
      u16x8 au;
      au[0] = f2bf(a0.x); au[1] = f2bf(a0.y); au[2] = f2bf(a0.z); au[3] = f2bf(a0.w);
      au[4] = f2bf(a1.x); au[5] = f2bf(a1.y); au[6] = f2bf(a1.z); au[7] = f2bf(a1.w);
      av[kk] = au;
    }
    #pragma unroll
    for (int g = 0; g < 6; ++g) {
      f32x4 acc[4];
      const f32x4 z = {0.f, 0.f, 0.f, 0.f};
      acc[0] = z; acc[1] = z; acc[2] = z; acc[3] = z;
      #pragma unroll
      for (int kk = 0; kk < 4; ++kk) {
        #pragma unroll
        for (int s = 0; s < 4; ++s) {
          u16x8 bu = *(const u16x8*)(CW + (size_t)(g * 64 + s * 16 + r16) * DIM + kk * 32 + quad * 8);
          acc[s] = __builtin_amdgcn_mfma_f32_16x16x32_bf16(
              __builtin_bit_cast(bf16x8, av[kk]), __builtin_bit_cast(bf16x8, bu), acc[s], 0, 0, 0);
        }
      }
      const int arr = g >> 1;               // 0:q 1:K 2:V
      const int colbase = (g & 1) * 64;
      unsigned short* dst = arr == 0 ? qb : (arr == 1 ? Kb : Vb);
      #pragma unroll
      for (int s = 0; s < 4; ++s) {
        int j = colbase + s * 16 + r16;
        float bias = arr == 0 ? 0.25f * bq[j] : (arr == 2 ? bv[j] : 0.f);
        #pragma unroll
        for (int r = 0; r < 4; ++r) {
          int m = m0 + quad * 4 + r;
          dst[(size_t)m * DIM + j] = f2bf(acc[s][r] + bias);
        }
      }
    }
  } else {
    const int idx = blockIdx.x - 512;
    const int m0 = (idx >> 1) * 64 + wave * 16;
    const int n0 = (idx & 1) * 64;
    f32x4 acc[4];
    const f32x4 z = {0.f, 0.f, 0.f, 0.f};
    acc[0] = z; acc[1] = z; acc[2] = z; acc[3] = z;
    const float* arow = ea + (size_t)(m0 + r16) * EDIM + quad * 8;
    #pragma unroll
    for (int kk = 0; kk < 2; ++kk) {
      float4 a0 = *(const float4*)(arow + kk * 32);
      float4 a1 = *(const float4*)(arow + kk * 32 + 4);
      u16x8 au;
      au[0] = f2bf(a0.x); au[1] = f2bf(a0.y); au[2] = f2bf(a0.z); au[3] = f2bf(a0.w);
      au[4] = f2bf(a1.x); au[5] = f2bf(a1.y); au[6] = f2bf(a1.z); au[7] = f2bf(a1.w);
      bf16x8 av = __builtin_bit_cast(bf16x8, au);
      #pragma unroll
      for (int s = 0; s < 4; ++s) {
        u16x8 bu = *(const u16x8*)(CWE + (size_t)(n0 + s * 16 + r16) * EDIM + kk * 32 + quad * 8);
        acc[s] = __builtin_amdgcn_mfma_f32_16x16x32_bf16(
            av, __builtin_bit_cast(bf16x8, bu), acc[s], 0, 0, 0);
      }
    }
    #pragma unroll
    for (int s = 0; s < 4; ++s) {
      int j = n0 + s * 16 + r16;
      float bias = bk[j];
      #pragma unroll
      for (int r = 0; r < 4; ++r) {
        int m = m0 + quad * 4 + r;
        WeKb[(size_t)m * DIM + j] = f2bf(acc[s][r] + bias);
      }
    }
  }
}

// ---------------- G2b: per-edge key materialization ---------------------------
// Ke[e][k][:] = bf16( Kb[enodes[e][k]][:] + WeKb[e][:] ), e in [0,E), k in [0,8).
// Each hyperedge is shared by ~8 nodes: doing this once here removes 8x
// redundant WeK dot-work and turns attn's K access into contiguous 4 KB
// edge blocks with a uniform base (no per-row index chain).
// 1 wave = 1 edge; all loads coalesced 256 B row reads; 16384 waves total.
__global__ __launch_bounds__(256) void g2b_kernel(
    const unsigned short* __restrict__ Kb, const unsigned short* __restrict__ WeKb,
    const int* __restrict__ enodes, unsigned short* __restrict__ Ke)
{
  const int wave = threadIdx.x >> 6, lane = threadIdx.x & 63;
  const int e = blockIdx.x * 4 + wave;

  const int* ep = enodes + (size_t)e * KPE;
  i32x4 a = *(const i32x4*)ep;
  i32x4 b = *(const i32x4*)(ep + 4);
  u32 we = ((const u32*)(WeKb + (size_t)e * DIM))[lane];

  int id[8] = {a.x, a.y, a.z, a.w, b.x, b.y, b.z, b.w};
  u32 kr[8];
  #pragma unroll
  for (int t = 0; t < 8; ++t)
    kr[t] = ((const u32*)(Kb + (size_t)id[t] * DIM))[lane];

  const float wl = bflo(we), wh = bfhi(we);
  u32* out = (u32*)(Ke + (size_t)e * KPE * DIM);
  #pragma unroll
  for (int t = 0; t < 8; ++t) {
    u32 pk = (u32)f2bf(bflo(kr[t]) + wl) | ((u32)f2bf(bfhi(kr[t]) + wh) << 16);
    out[t * (DIM / 2) + lane] = pk;
  }
}

// ---------------- G3: per-node attention (1 block = 1 wave = 1 node) ----------
// r8: K comes from the Ke edge-table straight into REGISTERS.
//  - no ldsK/ldsE, no LDS DMA: LDS = 1.2 KB (P only) -> occupancy cap moves
//    from LDS (was 11 KB -> ~10 waves/CU) to VGPR (~12 waves/CU at 168).
//  - score loop halves (WeK pre-added in Ke): 32 dot2bf/lane vs 64.
//  - VMEM per wave: 9 idx + 8 q + 8 K + 32 V + 1 store = 58 (was 85).
//  - all consumed data is register-resident, so the COMPILER's precise vmcnt
//    tracking handles every wait; the empty-asm fences only pin issue order
//    (idx/q -> K -> V) so the 32 V loads are youngest and stay in flight
//    under score+softmax.
__global__ __launch_bounds__(64, 3) void attn_kernel(
    const unsigned short* __restrict__ qb, const unsigned short* __restrict__ Ke,
    const unsigned short* __restrict__ Vb,
    const int* __restrict__ nedges, const int* __restrict__ uidx,
    unsigned short* __restrict__ ctxb)
{
  __shared__ __align__(16) float ldsP[8][36];              // P, padded stride
  const int lane = threadIdx.x;
  const int n = blockIdx.x;
  const int l = lane & 31, half = lane >> 5;
  const int h = lane >> 3;                                 // ctx head
  const int c0 = lane * 2;                                 // ctx dim pair

  // --- region 1: indices + q (independent; idx oldest) ---
  i32x4 e4 = __builtin_nontemporal_load((const i32x4*)(nedges + (size_t)n * DEG));
  const i32x4* up = (const i32x4*)(uidx + (size_t)n * 32);
  i32x4 m0 = __builtin_nontemporal_load(up + 0);
  i32x4 m1 = __builtin_nontemporal_load(up + 1);
  i32x4 m2 = __builtin_nontemporal_load(up + 2);
  i32x4 m3 = __builtin_nontemporal_load(up + 3);
  i32x4 m4 = __builtin_nontemporal_load(up + 4);
  i32x4 m5 = __builtin_nontemporal_load(up + 5);
  i32x4 m6 = __builtin_nontemporal_load(up + 6);
  i32x4 m7 = __builtin_nontemporal_load(up + 7);

  const u32x4* qp = (const u32x4*)(qb + (size_t)n * DIM + half * 64);
  u32x4 qv[8];
  #pragma unroll
  for (int ch = 0; ch < 8; ++ch) qv[ch] = __builtin_nontemporal_load(qp + ch);

  asm volatile("" ::: "memory");

  // --- region 2: K rows from Ke, per-lane gather into regs (8 x dwordx4) ---
  // lane l -> key l: edge slot d = l>>3, member k = l&7.
  const int d = l >> 3, kk = l & 7;
  int el = d == 0 ? e4.x : (d == 1 ? e4.y : (d == 2 ? e4.z : e4.w));
  const unsigned short* krow = Ke + ((size_t)el * KPE + kk) * DIM + half * 64;
  u32x4 kc[8];
  #pragma unroll
  for (int ch = 0; ch < 8; ++ch) kc[ch] = *(const u32x4*)(krow + ch * 8);

  asm volatile("" ::: "memory");

  // --- region 3: V rows (coalesced 256 B wave reads), youngest 32 VMEM ---
  u32 vv[32];
#define VLOAD(t, row) vv[t] = *(const u32*)(Vb + (size_t)(row) * DIM + c0)
  VLOAD(0,  m0.x); VLOAD(1,  m0.y); VLOAD(2,  m0.z); VLOAD(3,  m0.w);
  VLOAD(4,  m1.x); VLOAD(5,  m1.y); VLOAD(6,  m1.z); VLOAD(7,  m1.w);
  VLOAD(8,  m2.x); VLOAD(9,  m2.y); VLOAD(10, m2.z); VLOAD(11, m2.w);
  VLOAD(12, m3.x); VLOAD(13, m3.y); VLOAD(14, m3.z); VLOAD(15, m3.w);
  VLOAD(16, m4.x); VLOAD(17, m4.y); VLOAD(18, m4.z); VLOAD(19, m4.w);
  VLOAD(20, m5.x); VLOAD(21, m5.y); VLOAD(22, m5.z); VLOAD(23, m5.w);
  VLOAD(24, m6.x); VLOAD(25, m6.y); VLOAD(26, m6.z); VLOAD(27, m6.w);
  VLOAD(28, m7.x); VLOAD(29, m7.y); VLOAD(30, m7.z); VLOAD(31, m7.w);
#undef VLOAD

  asm volatile("" ::: "memory");

  // --- scores: s[hi] = q . Ke_row over this half's 64 dims (regs only) ---
  float s[4] = {0.f, 0.f, 0.f, 0.f};
  #pragma unroll
  for (int ch = 0; ch < 8; ++ch) {
    const int hi = ch >> 1;
    float t = s[hi];
    t = dot2bf(qv[ch].x, kc[ch].x, t);
    t = dot2bf(qv[ch].y, kc[ch].y, t);
    t = dot2bf(qv[ch].z, kc[ch].z, t);
    t = dot2bf(qv[ch].w, kc[ch].w, t);
    s[hi] = t;
  }

  // --- softmax over the 32 keys (within each 32-lane half-group) ---
  #pragma unroll
  for (int hi = 0; hi < 4; ++hi) {
    float vmax = s[hi];
    #pragma unroll
    for (int off = 16; off >= 1; off >>= 1)
      vmax = fmaxf(vmax, __shfl_xor(vmax, off, 32));
    float ex = __expf(s[hi] - vmax);
    float sum = ex;
    #pragma unroll
    for (int off = 16; off >= 1; off >>= 1)
      sum += __shfl_xor(sum, off, 32);
    ldsP[half * 4 + hi][l] = ex / sum;
  }
  // single-wave block: LDS write->read ordering is just lgkmcnt (compiler).

  // --- ctx: lane = dim pair; V regs (compiler waits precisely), P via LDS ---
  float a0 = 0.f, a1 = 0.f;
  #pragma unroll
  for (int t = 0; t < 8; ++t) {
    float4 p4 = *(const float4*)&ldsP[h][t * 4];
    a0 = fmaf(p4.x, bflo(vv[t * 4 + 0]), a0); a1 = fmaf(p4.x, bfhi(vv[t * 4 + 0]), a1);
    a0 = fmaf(p4.y, bflo(vv[t * 4 + 1]), a0); a1 = fmaf(p4.y, bfhi(vv[t * 4 + 1]), a1);
    a0 = fmaf(p4.z, bflo(vv[t * 4 + 2]), a0); a1 = fmaf(p4.z, bfhi(vv[t * 4 + 2]), a1);
    a0 = fmaf(p4.w, bflo(vv[t * 4 + 3]), a0); a1 = fmaf(p4.w, bfhi(vv[t * 4 + 3]), a1);
  }
  unsigned int pk = (unsigned int)f2bf(a0) | ((unsigned int)f2bf(a1) << 16);
  __builtin_nontemporal_store(pk, (u32*)(ctxb + (size_t)n * DIM + c0));
}

// ---------------- G4: ctx[N,128] @ Wo[128,128]^T + bo, ReLU -> out fp32 -------
__global__ __launch_bounds__(256) void g4_kernel(
    const unsigned short* __restrict__ ctxb, const unsigned short* __restrict__ Wob,
    const float* __restrict__ bo, float* __restrict__ out)
{
  const int wave = threadIdx.x >> 6, lane = threadIdx.x & 63;
  const int r16 = lane & 15, quad = lane >> 4;
  const int m0 = blockIdx.x * 64 + wave * 16;
  const int n0 = blockIdx.y * 64;

  f32x4 acc[4];
  const f32x4 z = {0.f, 0.f, 0.f, 0.f};
  acc[0] = z; acc[1] = z; acc[2] = z; acc[3] = z;

  #pragma unroll
  for (int kk = 0; kk < 4; ++kk) {
    u16x8 au = *(const u16x8*)(ctxb + (size_t)(m0 + r16) * DIM + kk * 32 + quad * 8);
    bf16x8 av = __builtin_bit_cast(bf16x8, au);
    #pragma unroll
    for (int s = 0; s < 4; ++s) {
      u16x8 bu = *(const u16x8*)(Wob + (size_t)(n0 + s * 16 + r16) * DIM + kk * 32 + quad * 8);
      acc[s] = __builtin_amdgcn_mfma_f32_16x16x32_bf16(
          av, __builtin_bit_cast(bf16x8, bu), acc[s], 0, 0, 0);
    }
  }

  #pragma unroll
  for (int s = 0; s < 4; ++s) {
    int j = n0 + s * 16 + r16;
    float bias = bo[j];
    #pragma unroll
    for (int r = 0; r < 4; ++r) {
      int m = m0 + quad * 4 + r;
      float v = acc[s][r] + bias;
      out[(size_t)m * DIM + j] = v > 0.f ? v : 0.f;
    }
  }
}

extern "C" void kernel_launch(void* const* d_in, const int* in_sizes, int n_in,
                              void* d_out, int out_size, void* d_ws, size_t ws_size,
                              hipStream_t stream)
{
  const float* x     = (const float*)d_in[0];
  const float* ea    = (const float*)d_in[1];
  const int* nedges  = (const int*)d_in[2];
  const int* enodes  = (const int*)d_in[3];
  const float* Wlin  = (const float*)d_in[4];
  const float* Wedge = (const float*)d_in[5];
  const float* Wq    = (const float*)d_in[6];
  const float* Wk    = (const float*)d_in[7];
  const float* Wv    = (const float*)d_in[8];
  const float* bq    = (const float*)d_in[9];
  const float* bk    = (const float*)d_in[10];
  const float* bv    = (const float*)d_in[11];
  const float* Wo    = (const float*)d_in[12];
  const float* bo    = (const float*)d_in[13];
  float* out = (float*)d_out;

  unsigned short* wsp = (unsigned short*)d_ws;
  unsigned short* CW   = wsp;  wsp += 384 * 128;
  unsigned short* CWE  = wsp;  wsp += 128 * 64;
  unsigned short* Wob  = wsp;  wsp += 128 * 128;
  unsigned short* qb   = wsp;  wsp += (size_t)N_NODES * DIM;
  unsigned short* Kb   = wsp;  wsp += (size_t)N_NODES * DIM;
  unsigned short* Vb   = wsp;  wsp += (size_t)N_NODES * DIM;
  unsigned short* WeKb = wsp;  wsp += (size_t)N_EDGES * DIM;
  unsigned short* ctxb = wsp;  wsp += (size_t)N_NODES * DIM;
  int* uidx = (int*)wsp;       wsp += (size_t)N_NODES * 32 * 2;  // 32 ints/node
  unsigned short* Ke   = wsp;  wsp += (size_t)N_EDGES * KPE * DIM;  // 33.5 MB

  wprep_kernel<<<dim3(800), dim3(256), 0, stream>>>(
      Wq, Wk, Wv, Wlin, Wedge, Wo, nedges, enodes, CW, CWE, Wob, uidx);
  g12_kernel<<<dim3(1024), dim3(256), 0, stream>>>(x, CW, bq, bv, qb, Kb, Vb, ea, CWE, bk, WeKb);
  g2b_kernel<<<dim3(N_EDGES / 4), dim3(256), 0, stream>>>(Kb, WeKb, enodes, Ke);
  attn_kernel<<<dim3(32768), dim3(64), 0, stream>>>(qb, Ke, Vb, nedges, uidx, ctxb);
  g4_kernel<<<dim3(512, 2), dim3(256), 0, stream>>>(ctxb, Wob, bo, out);
}

// Round 5
// 207.533 us; speedup vs baseline: 1.0583x; 1.0583x over previous
//
#include <hip/hip_runtime.h>

#define N_NODES 32768
#define N_EDGES 16384
#define DEG 4
#define KPE 8
#define DIM 128
#define EDIM 64
#define MAXC 64   // max containing-(node,slot) entries per edge; Poisson(8) -> P(>64) ~ 1e-40

typedef float f32x4 __attribute__((ext_vector_type(4)));
typedef __bf16 bf16x8 __attribute__((ext_vector_type(8)));
typedef __bf16 bf16x2 __attribute__((ext_vector_type(2)));
typedef unsigned short u16x8 __attribute__((ext_vector_type(8)));
typedef unsigned int u32;
typedef unsigned int u32x4 __attribute__((ext_vector_type(4)));
typedef int i32x4 __attribute__((ext_vector_type(4)));

static __device__ __forceinline__ unsigned short f2bf(float f) {
  union { float f; unsigned int u; } v; v.f = f;
  unsigned int r = (v.u + 0x7FFFu + ((v.u >> 16) & 1u)) >> 16;
  return (unsigned short)r;
}
static __device__ __forceinline__ float bflo(unsigned int v) {
  union { unsigned int u; float f; } x; x.u = v << 16; return x.f;
}
static __device__ __forceinline__ float bfhi(unsigned int v) {
  union { unsigned int u; float f; } x; x.u = v & 0xffff0000u; return x.f;
}
static __device__ __forceinline__ float f16tof(unsigned short h) {
  return (float)__builtin_bit_cast(_Float16, h);
}
static __device__ __forceinline__ unsigned short ftof16(float f) {
  return __builtin_bit_cast(unsigned short, (_Float16)f);
}

#if __has_builtin(__builtin_amdgcn_fdot2_f32_bf16)
static __device__ __forceinline__ float dot2bf(unsigned int a, unsigned int b, float c) {
  return __builtin_amdgcn_fdot2_f32_bf16(
      __builtin_bit_cast(bf16x2, a), __builtin_bit_cast(bf16x2, b), c, false);
}
#else
static __device__ __forceinline__ float dot2bf(unsigned int a, unsigned int b, float c) {
  c = fmaf(bflo(a), bflo(b), c);
  return fmaf(bfhi(a), bfhi(b), c);
}
#endif

// ---------------- zero the per-edge counters (must precede wprep atomics) -----
__global__ __launch_bounds__(256) void zcnt_kernel(int* __restrict__ cnt)
{
  cnt[blockIdx.x * 256 + threadIdx.x] = 0;
}

// ---------------- weight combine + reverse-CSR build --------------------------
// CW=[0.25*Wq@Wlin; Wk@Wlin; Wv@Wlin], CWE=Wk@Wedge(+fold), Wob=bf16(Wo).
// rev[e][0..cnt[e]) = packed (n*4+d) for every (n,d) with node_edges[n][d]==e.
// Slot order is atomic-nondeterministic but each entry writes its own (n,d)
// output slot downstream, so results are order-independent.
__global__ __launch_bounds__(256) void wprep_kernel(
    const float* __restrict__ Wq, const float* __restrict__ Wk,
    const float* __restrict__ Wv, const float* __restrict__ Wlin,
    const float* __restrict__ Wedge, const float* __restrict__ Wo,
    const int* __restrict__ node_edges,
    unsigned short* __restrict__ CW, unsigned short* __restrict__ CWE,
    unsigned short* __restrict__ Wob, int* __restrict__ cnt, int* __restrict__ rev)
{
  int id = blockIdx.x * 256 + threadIdx.x;
  if (id < 384 * 128) {
    int j = id >> 7, i = id & 127;
    const float* wrow; float scale = 1.0f;
    if (j < 128)      { wrow = Wq + j * 128; scale = 0.25f; }
    else if (j < 256) { wrow = Wk + (j - 128) * 128; }
    else              { wrow = Wv + (j - 256) * 128; }
    float s = 0.f;
    #pragma unroll 8
    for (int m = 0; m < 128; ++m) s += wrow[m] * Wlin[m * 128 + i];
    CW[id] = f2bf(s * scale);
  } else if (id < 384 * 128 + 128 * 64) {
    int id2 = id - 384 * 128; int j = id2 >> 6, t = id2 & 63;
    float s = 0.f;
    #pragma unroll 8
    for (int m = 0; m < 128; ++m) s += Wk[j * 128 + m] * Wedge[m * 64 + t];
    CWE[id2] = f2bf(s);
  } else if (id < 384 * 128 + 128 * 64 + 128 * 128) {
    int id3 = id - (384 * 128 + 128 * 64);
    Wob[id3] = f2bf(Wo[id3]);
  } else {
    int t = id - (384 * 128 + 128 * 64 + 128 * 128);   // t = n*DEG + d
    if (t < N_NODES * DEG) {
      int e = node_edges[t];
      int pos = atomicAdd(&cnt[e], 1);
      if (pos < MAXC) rev[(size_t)e * MAXC + pos] = t;
    }
  }
}

// ---------------- G12: fused g1 + g2 (unchanged) ------------------------------
__global__ __launch_bounds__(256) void g12_kernel(
    const float* __restrict__ x, const unsigned short* __restrict__ CW,
    const float* __restrict__ bq, const float* __restrict__ bv,
    unsigned short* __restrict__ qb, unsigned short* __restrict__ Kb,
    unsigned short* __restrict__ Vb,
    const float* __restrict__ ea, const unsigned short* __restrict__ CWE,
    const float* __restrict__ bk, unsigned short* __restrict__ WeKb)
{
  const int wave = threadIdx.x >> 6, lane = threadIdx.x & 63;
  const int r16 = lane & 15, quad = lane >> 4;

  if (blockIdx.x < 512) {
    const int m0 = blockIdx.x * 64 + wave * 16;
    u16x8 av[4];
    const float* arow = x + (size_t)(m0 + r16) * DIM + quad * 8;
    #pragma unroll
    for (int kk = 0; kk < 4; ++kk) {
      float4 a0 = *(const float4*)(arow + kk * 32);
      float4 a1 = *(const float4*)(arow + kk * 32 + 4);
      u16x8 au;
      au[0] = f2bf(a0.x); au[1] = f2bf(a0.y); au[2] = f2bf(a0.z); au[3] = f2bf(a0.w);
      au[4] = f2bf(a1.x); au[5] = f2bf(a1.y); au[6] = f2bf(a1.z); au[7] = f2bf(a1.w);
      av[kk] = au;
    }
    #pragma unroll
    for (int g = 0; g < 6; ++g) {
      f32x4 acc[4];
      const f32x4 z = {0.f, 0.f, 0.f, 0.f};
      acc[0] = z; acc[1] = z; acc[2] = z; acc[3] = z;
      #pragma unroll
      for (int kk = 0; kk < 4; ++kk) {
        #pragma unroll
        for (int s = 0; s < 4; ++s) {
          u16x8 bu = *(const u16x8*)(CW + (size_t)(g * 64 + s * 16 + r16) * DIM + kk * 32 + quad * 8);
          acc[s] = __builtin_amdgcn_mfma_f32_16x16x32_bf16(
              __builtin_bit_cast(bf16x8, av[kk]), __builtin_bit_cast(bf16x8, bu), acc[s], 0, 0, 0);
        }
      }
      const int arr = g >> 1;               // 0:q 1:K 2:V
      const int colbase = (g & 1) * 64;
      unsigned short* dst = arr == 0 ? qb : (arr == 1 ? Kb : Vb);
      #pragma unroll
      for (int s = 0; s < 4; ++s) {
        int j = colbase + s * 16 + r16;
        float bias = arr == 0 ? 0.25f * bq[j] : (arr == 2 ? bv[j] : 0.f);
        #pragma unroll
        for (int r = 0; r < 4; ++r) {
          int m = m0 + quad * 4 + r;
          dst[(size_t)m * DIM + j] = f2bf(acc[s][r] + bias);
        }
      }
    }
  } else {
    const int idx = blockIdx.x - 512;
    const int m0 = (idx >> 1) * 64 + wave * 16;
    const int n0 = (idx & 1) * 64;
    f32x4 acc[4];
    const f32x4 z = {0.f, 0.f, 0.f, 0.f};
    acc[0] = z; acc[1] = z; acc[2] = z; acc[3] = z;
    const float* arow = ea + (size_t)(m0 + r16) * EDIM + quad * 8;
    #pragma unroll
    for (int kk = 0; kk < 2; ++kk) {
      float4 a0 = *(const float4*)(arow + kk * 32);
      float4 a1 = *(const float4*)(arow + kk * 32 + 4);
      u16x8 au;
      au[0] = f2bf(a0.x); au[1] = f2bf(a0.y); au[2] = f2bf(a0.z); au[3] = f2bf(a0.w);
      au[4] = f2bf(a1.x); au[5] = f2bf(a1.y); au[6] = f2bf(a1.z); au[7] = f2bf(a1.w);
      bf16x8 av = __builtin_bit_cast(bf16x8, au);
      #pragma unroll
      for (int s = 0; s < 4; ++s) {
        u16x8 bu = *(const u16x8*)(CWE + (size_t)(n0 + s * 16 + r16) * EDIM + kk * 32 + quad * 8);
        acc[s] = __builtin_amdgcn_mfma_f32_16x16x32_bf16(
            av, __builtin_bit_cast(bf16x8, bu), acc[s], 0, 0, 0);
      }
    }
    #pragma unroll
    for (int s = 0; s < 4; ++s) {
      int j = n0 + s * 16 + r16;
      float bias = bk[j];
      #pragma unroll
      for (int r = 0; r < 4; ++r) {
        int m = m0 + quad * 4 + r;
        WeKb[(size_t)m * DIM + j] = f2bf(acc[s][r] + bias);
      }
    }
  }
}

// ---------------- ESCORE: per-edge score kernel -------------------------------
// 1 wave = 1 edge. Lane = (member g = lane>>3, head j = lane&7). Each lane's
// 16-dim chunk IS head j, so a lane's local dot is a complete head score:
// no cross-lane reduction. Per containing entry c (=(n,d) from rev):
//   gather q[n] chunk (32 B/lane, 8-way dup merged), 16 dot2bf,
//   coalesced 128 B store S[n][l=d*8+g][h=j] (fp16).
// K-rows read once per edge (~4x total per row) instead of once per
// containing node (~32x) -- the 8x gather-traffic cut this round is about.
__global__ __launch_bounds__(256) void escore_kernel(
    const unsigned short* __restrict__ qb, const unsigned short* __restrict__ Kb,
    const unsigned short* __restrict__ WeKb, const int* __restrict__ enodes,
    const int* __restrict__ cnt, const int* __restrict__ rev,
    unsigned short* __restrict__ S)
{
  const int wave = threadIdx.x >> 6, lane = threadIdx.x & 63;
  const int e = blockIdx.x * 4 + wave;
  const int g = lane >> 3, j = lane & 7;

  int c_n = cnt[e]; if (c_n > MAXC) c_n = MAXC;
  if (c_n == 0) return;
  int rv = rev[(size_t)e * MAXC + lane];

  int mid = enodes[(size_t)e * KPE + g];
  u32x4 k0 = *(const u32x4*)(Kb + (size_t)mid * DIM + j * 16);
  u32x4 k1 = *(const u32x4*)(Kb + (size_t)mid * DIM + j * 16 + 8);
  u32x4 w0 = *(const u32x4*)(WeKb + (size_t)e * DIM + j * 16);
  u32x4 w1 = *(const u32x4*)(WeKb + (size_t)e * DIM + j * 16 + 8);

  int pk = __shfl(rv, 0);
  u32x4 qa0 = *(const u32x4*)(qb + (size_t)(pk >> 2) * DIM + j * 16);
  u32x4 qa1 = *(const u32x4*)(qb + (size_t)(pk >> 2) * DIM + j * 16 + 8);

  for (int c = 0; c < c_n; ++c) {
    const int n = pk >> 2, d = pk & 3;
    u32x4 q0 = qa0, q1 = qa1;
    if (c + 1 < c_n) {
      pk = __shfl(rv, c + 1);
      qa0 = *(const u32x4*)(qb + (size_t)(pk >> 2) * DIM + j * 16);
      qa1 = *(const u32x4*)(qb + (size_t)(pk >> 2) * DIM + j * 16 + 8);
    }
    float s = 0.f;
    s = dot2bf(q0.x, k0.x, s); s = dot2bf(q0.y, k0.y, s);
    s = dot2bf(q0.z, k0.z, s); s = dot2bf(q0.w, k0.w, s);
    s = dot2bf(q1.x, k1.x, s); s = dot2bf(q1.y, k1.y, s);
    s = dot2bf(q1.z, k1.z, s); s = dot2bf(q1.w, k1.w, s);
    s = dot2bf(q0.x, w0.x, s); s = dot2bf(q0.y, w0.y, s);
    s = dot2bf(q0.z, w0.z, s); s = dot2bf(q0.w, w0.w, s);
    s = dot2bf(q1.x, w1.x, s); s = dot2bf(q1.y, w1.y, s);
    s = dot2bf(q1.z, w1.z, s); s = dot2bf(q1.w, w1.w, s);
    // S[n][key=d*8+g][head=j], fp16: flat ushort idx = n*256 + d*64 + g*8 + j
    S[(size_t)n * 256 + d * 64 + g * 8 + j] = ftof16(s);
  }
}

// ---------------- NSM: per-node softmax, S[n][l][h] -> P[n][h][l] in place ----
// 1 wave = 1 node. Lane = (hp = lane>>5 selects heads hp*4..hp*4+3, l = key).
// Reads the node's full 512 B S row into regs, then overwrites with P (same
// 512 B region, own-wave only -> no race). fp16 keeps logit error ~1e-3.
__global__ __launch_bounds__(256) void nsm_kernel(unsigned short* __restrict__ SP)
{
  const int wave = threadIdx.x >> 6, lane = threadIdx.x & 63;
  const int n = blockIdx.x * 4 + wave;
  const int l = lane & 31, hp = lane >> 5;
  unsigned short* row = SP + (size_t)n * 256;

  uint2 sv = *(const uint2*)(row + l * 8 + hp * 4);
  float s4[4] = { f16tof(sv.x & 0xffff), f16tof(sv.x >> 16),
                  f16tof(sv.y & 0xffff), f16tof(sv.y >> 16) };
  unsigned short pr[4];
  #pragma unroll
  for (int hi = 0; hi < 4; ++hi) {
    float vmax = s4[hi];
    #pragma unroll
    for (int off = 16; off >= 1; off >>= 1)
      vmax = fmaxf(vmax, __shfl_xor(vmax, off, 32));
    float ex = __expf(s4[hi] - vmax);
    float sum = ex;
    #pragma unroll
    for (int off = 16; off >= 1; off >>= 1)
      sum += __shfl_xor(sum, off, 32);
    pr[hi] = ftof16(ex / sum);
  }
  #pragma unroll
  for (int hi = 0; hi < 4; ++hi)
    row[(hp * 4 + hi) * 32 + l] = pr[hi];
}

// ---------------- ECTX: per-edge context partials -----------------------------
// 1 wave = 1 edge. Lane = dim pair (c0 = lane*2, head h = lane>>3).
// V rows read once per edge (8 coalesced 256 B reads). Per containing entry c:
// 16 B P gather + 16 fma + coalesced 256 B store of ctxp[n][d] (fp16 partial).
__global__ __launch_bounds__(256) void ectx_kernel(
    const unsigned short* __restrict__ Vb, const unsigned short* __restrict__ P,
    const int* __restrict__ enodes, const int* __restrict__ cnt,
    const int* __restrict__ rev, unsigned short* __restrict__ ctxp)
{
  const int wave = threadIdx.x >> 6, lane = threadIdx.x & 63;
  const int e = blockIdx.x * 4 + wave;
  const int c0 = lane * 2, h = lane >> 3;

  int c_n = cnt[e]; if (c_n > MAXC) c_n = MAXC;
  if (c_n == 0) return;
  int rv = rev[(size_t)e * MAXC + lane];

  const int* ep = enodes + (size_t)e * KPE;
  i32x4 a4 = *(const i32x4*)ep;
  i32x4 b4 = *(const i32x4*)(ep + 4);
  int id[8] = {a4.x, a4.y, a4.z, a4.w, b4.x, b4.y, b4.z, b4.w};
  u32 vv[8];
  #pragma unroll
  for (int k = 0; k < 8; ++k) vv[k] = *(const u32*)(Vb + (size_t)id[k] * DIM + c0);

  int pk = __shfl(rv, 0);
  uint4 pva = *(const uint4*)(P + (size_t)(pk >> 2) * 256 + h * 32 + (pk & 3) * 8);

  for (int c = 0; c < c_n; ++c) {
    const int n = pk >> 2, d = pk & 3;
    uint4 pv = pva;
    if (c + 1 < c_n) {
      pk = __shfl(rv, c + 1);
      pva = *(const uint4*)(P + (size_t)(pk >> 2) * 256 + h * 32 + (pk & 3) * 8);
    }
    float p0 = f16tof(pv.x & 0xffff), p1 = f16tof(pv.x >> 16);
    float p2 = f16tof(pv.y & 0xffff), p3 = f16tof(pv.y >> 16);
    float p4 = f16tof(pv.z & 0xffff), p5 = f16tof(pv.z >> 16);
    float p6 = f16tof(pv.w & 0xffff), p7 = f16tof(pv.w >> 16);
    float a0 = 0.f, a1 = 0.f;
    a0 = fmaf(p0, bflo(vv[0]), a0); a1 = fmaf(p0, bfhi(vv[0]), a1);
    a0 = fmaf(p1, bflo(vv[1]), a0); a1 = fmaf(p1, bfhi(vv[1]), a1);
    a0 = fmaf(p2, bflo(vv[2]), a0); a1 = fmaf(p2, bfhi(vv[2]), a1);
    a0 = fmaf(p3, bflo(vv[3]), a0); a1 = fmaf(p3, bfhi(vv[3]), a1);
    a0 = fmaf(p4, bflo(vv[4]), a0); a1 = fmaf(p4, bfhi(vv[4]), a1);
    a0 = fmaf(p5, bflo(vv[5]), a0); a1 = fmaf(p5, bfhi(vv[5]), a1);
    a0 = fmaf(p6, bflo(vv[6]), a0); a1 = fmaf(p6, bfhi(vv[6]), a1);
    a0 = fmaf(p7, bflo(vv[7]), a0); a1 = fmaf(p7, bfhi(vv[7]), a1);
    u32 pk2 = (u32)ftof16(a0) | ((u32)ftof16(a1) << 16);
    *(u32*)(ctxp + ((size_t)n * 4 + d) * DIM + c0) = pk2;
  }
}

// ---------------- G4: (sum of 4 fp16 partials) @ Wo^T + bo, ReLU --------------
// Each block: 64 rows x all 128 cols (combined partials reused for both halves).
__global__ __launch_bounds__(256) void g4_kernel(
    const unsigned short* __restrict__ ctxp, const unsigned short* __restrict__ Wob,
    const float* __restrict__ bo, float* __restrict__ out)
{
  const int wave = threadIdx.x >> 6, lane = threadIdx.x & 63;
  const int r16 = lane & 15, quad = lane >> 4;
  const int m0 = blockIdx.x * 64 + wave * 16;

  f32x4 acc[2][4];
  const f32x4 z = {0.f, 0.f, 0.f, 0.f};
  #pragma unroll
  for (int hf = 0; hf < 2; ++hf) { acc[hf][0] = z; acc[hf][1] = z; acc[hf][2] = z; acc[hf][3] = z; }

  #pragma unroll
  for (int kk = 0; kk < 4; ++kk) {
    float fa[8] = {0.f, 0.f, 0.f, 0.f, 0.f, 0.f, 0.f, 0.f};
    #pragma unroll
    for (int d = 0; d < 4; ++d) {
      u16x8 t = *(const u16x8*)(ctxp + ((size_t)(m0 + r16) * 4 + d) * DIM + kk * 32 + quad * 8);
      #pragma unroll
      for (int i = 0; i < 8; ++i) fa[i] += f16tof(t[i]);
    }
    u16x8 au;
    #pragma unroll
    for (int i = 0; i < 8; ++i) au[i] = f2bf(fa[i]);
    bf16x8 av = __builtin_bit_cast(bf16x8, au);
    #pragma unroll
    for (int hf = 0; hf < 2; ++hf) {
      #pragma unroll
      for (int s = 0; s < 4; ++s) {
        u16x8 bu = *(const u16x8*)(Wob + (size_t)(hf * 64 + s * 16 + r16) * DIM + kk * 32 + quad * 8);
        acc[hf][s] = __builtin_amdgcn_mfma_f32_16x16x32_bf16(
            av, __builtin_bit_cast(bf16x8, bu), acc[hf][s], 0, 0, 0);
      }
    }
  }

  #pragma unroll
  for (int hf = 0; hf < 2; ++hf) {
    #pragma unroll
    for (int s = 0; s < 4; ++s) {
      int jj = hf * 64 + s * 16 + r16;
      float bias = bo[jj];
      #pragma unroll
      for (int r = 0; r < 4; ++r) {
        int m = m0 + quad * 4 + r;
        float v = acc[hf][s][r] + bias;
        out[(size_t)m * DIM + jj] = v > 0.f ? v : 0.f;
      }
    }
  }
}

extern "C" void kernel_launch(void* const* d_in, const int* in_sizes, int n_in,
                              void* d_out, int out_size, void* d_ws, size_t ws_size,
                              hipStream_t stream)
{
  const float* x     = (const float*)d_in[0];
  const float* ea    = (const float*)d_in[1];
  const int* nedges  = (const int*)d_in[2];
  const int* enodes  = (const int*)d_in[3];
  const float* Wlin  = (const float*)d_in[4];
  const float* Wedge = (const float*)d_in[5];
  const float* Wq    = (const float*)d_in[6];
  const float* Wk    = (const float*)d_in[7];
  const float* Wv    = (const float*)d_in[8];
  const float* bq    = (const float*)d_in[9];
  const float* bk    = (const float*)d_in[10];
  const float* bv    = (const float*)d_in[11];
  const float* Wo    = (const float*)d_in[12];
  const float* bo    = (const float*)d_in[13];
  float* out = (float*)d_out;

  unsigned short* wsp = (unsigned short*)d_ws;
  unsigned short* CW   = wsp;  wsp += 384 * 128;
  unsigned short* CWE  = wsp;  wsp += 128 * 64;
  unsigned short* Wob  = wsp;  wsp += 128 * 128;
  unsigned short* qb   = wsp;  wsp += (size_t)N_NODES * DIM;
  unsigned short* Kb   = wsp;  wsp += (size_t)N_NODES * DIM;
  unsigned short* Vb   = wsp;  wsp += (size_t)N_NODES * DIM;
  unsigned short* WeKb = wsp;  wsp += (size_t)N_EDGES * DIM;
  unsigned short* SP   = wsp;  wsp += (size_t)N_NODES * 256;      // fp16 S -> P in place (16 MB)
  unsigned short* ctxp = wsp;  wsp += (size_t)N_NODES * 4 * DIM;  // fp16 partials (33.5 MB)
  int* cnt = (int*)wsp;        wsp += N_EDGES * 2;
  int* rev = (int*)wsp;        wsp += (size_t)N_EDGES * MAXC * 2;

  zcnt_kernel<<<dim3(64), dim3(256), 0, stream>>>(cnt);
  wprep_kernel<<<dim3(800), dim3(256), 0, stream>>>(
      Wq, Wk, Wv, Wlin, Wedge, Wo, nedges, CW, CWE, Wob, cnt, rev);
  g12_kernel<<<dim3(1024), dim3(256), 0, stream>>>(x, CW, bq, bv, qb, Kb, Vb, ea, CWE, bk, WeKb);
  escore_kernel<<<dim3(N_EDGES / 4), dim3(256), 0, stream>>>(qb, Kb, WeKb, enodes, cnt, rev, SP);
  nsm_kernel<<<dim3(N_NODES / 4), dim3(256), 0, stream>>>(SP);
  ectx_kernel<<<dim3(N_EDGES / 4), dim3(256), 0, stream>>>(Vb, SP, enodes, cnt, rev, ctxp);
  g4_kernel<<<dim3(512), dim3(256), 0, stream>>>(ctxp, Wob, bo, out);
}